// Round 1
// baseline (260.006 us; speedup 1.0000x reference)
//
#include <hip/hip_runtime.h>

typedef _Float16 half2_t __attribute__((ext_vector_type(2)));
typedef _Float16 half8_t __attribute__((ext_vector_type(8)));

constexpr int NX = 256, NU = 32, NY = 32, BATCH = 16, T = 8192;
constexpr int NC = 32, L = 256;     // 32 chunks of 256 steps
constexpr int SUBT = 32;            // t-subtile for projection
constexpr int KW = NX + NU;         // 288: [z | u] concatenated K
constexpr int ROWP = 296;           // padded row length in halves (592B, 16B-aligned)

// ---------------- pre: Bz = Q^T Bmat, Wh = [C Q | D] (f16), z0 = x0 Q ----------------
__global__ __launch_bounds__(256) void k_pre(
    const float* __restrict__ x0, const float* __restrict__ Q,
    const float* __restrict__ Bm, const float* __restrict__ C,
    const float* __restrict__ D,
    float* __restrict__ Bz, float* __restrict__ z0, _Float16* __restrict__ Wh)
{
    int gid = blockIdx.x * 256 + threadIdx.x;
    if (gid < 8192) {                       // Bz[n][j] = sum_k Q[k][n] * Bm[k][j]
        int n = gid >> 5, j = gid & 31;
        float s = 0.f;
        for (int k = 0; k < NX; ++k) s = fmaf(Q[k * NX + n], Bm[k * NU + j], s);
        Bz[n * NU + j] = s;
    } else if (gid < 16384) {               // Wh[iy][n] = (CQ)[iy][n]
        int g = gid - 8192; int iy = g >> 8, n = g & 255;
        float s = 0.f;
        for (int k = 0; k < NX; ++k) s = fmaf(C[iy * NX + k], Q[k * NX + n], s);
        Wh[iy * KW + n] = (_Float16)s;
    } else if (gid < 17408) {               // Wh[iy][256+j] = D[iy][j]
        int g = gid - 16384; int iy = g >> 5, j = g & 31;
        Wh[iy * KW + NX + j] = (_Float16)D[iy * NU + j];
    } else if (gid < 21504) {               // z0[b][n] = sum_k x0[b][k] Q[k][n]
        int g = gid - 17408; int b = g >> 8, n = g & 255;
        float s = 0.f;
        for (int k = 0; k < NX; ++k) s = fmaf(x0[b * NX + k], Q[k * NX + n], s);
        z0[b * NX + n] = s;
    }
}

// ---------------- phase 1: per-chunk local end states S (zero-init scan) ----------------
__global__ __launch_bounds__(256) void k_phase1(
    const float* __restrict__ u, const float* __restrict__ lam,
    const float* __restrict__ Bz, float* __restrict__ S)
{
    int b = blockIdx.x >> 5, c = blockIdx.x & 31, n = threadIdx.x;
    float br[NU];
    #pragma unroll
    for (int q = 0; q < NU / 4; ++q) {
        float4 t4 = ((const float4*)(Bz + n * NU))[q];
        br[4 * q] = t4.x; br[4 * q + 1] = t4.y; br[4 * q + 2] = t4.z; br[4 * q + 3] = t4.w;
    }
    float ln = lam[n];
    const float* ug = u + ((size_t)(b * T) + (size_t)c * L) * NU;
    float z = 0.f;
    for (int t = 0; t < L; ++t) {
        const float4* u4 = (const float4*)(ug + t * NU);   // block-uniform address
        float v0 = 0.f, v1 = 0.f, v2 = 0.f, v3 = 0.f;
        #pragma unroll
        for (int q = 0; q < 8; ++q) {
            float4 uu = u4[q];
            v0 = fmaf(br[4 * q], uu.x, v0);
            v1 = fmaf(br[4 * q + 1], uu.y, v1);
            v2 = fmaf(br[4 * q + 2], uu.z, v2);
            v3 = fmaf(br[4 * q + 3], uu.w, v3);
        }
        z = fmaf(ln, z, (v0 + v1) + (v2 + v3));
    }
    S[blockIdx.x * NX + n] = z;
}

// ---------------- phase 3: chunk-start fixup, re-scan, fused y projection ----------------
__global__ __launch_bounds__(256) void k_phase3(
    const float* __restrict__ u, const float* __restrict__ lam,
    const float* __restrict__ Bz, const float* __restrict__ z0w,
    const float* __restrict__ S, const _Float16* __restrict__ Wh,
    float* __restrict__ y)
{
    __shared__ __align__(16) _Float16 zt[SUBT][ROWP];  // [tt][0:256]=z_prev(f16), [256:288]=u(f16)
    __shared__ __align__(16) _Float16 wh[NY][ROWP];    // [iy][0:256]=Cz, [256:288]=D

    int b = blockIdx.x >> 5, c = blockIdx.x & 31, n = threadIdx.x;

    // stage W = [Cz | D] rows into padded LDS
    for (int i = n; i < NY * KW; i += 256) {
        int iy = i / KW, k = i - iy * KW;
        wh[iy][k] = Wh[i];
    }

    float br[NU];
    #pragma unroll
    for (int q = 0; q < NU / 4; ++q) {
        float4 t4 = ((const float4*)(Bz + n * NU))[q];
        br[4 * q] = t4.x; br[4 * q + 1] = t4.y; br[4 * q + 2] = t4.z; br[4 * q + 3] = t4.w;
    }
    float ln = lam[n];
    float lamL = ln;
    #pragma unroll
    for (int q = 0; q < 8; ++q) lamL *= lamL;          // lam^256

    // chunk-start state: P_c = lam^L * P_{c-1} + S_{c-1}, P_0 = z0
    float cur = z0w[b * NX + n];
    for (int cc = 0; cc < c; ++cc)
        cur = fmaf(lamL, cur, S[(b * NC + cc) * NX + n]);

    const float* ug = u + ((size_t)(b * T) + (size_t)c * L) * NU;
    float* yg = y + ((size_t)(b * T) + (size_t)c * L) * NY;
    __syncthreads();

    for (int sub = 0; sub < L / SUBT; ++sub) {
        const float* us = ug + sub * SUBT * NU;
        // scan subtile: record z_prev (f16), advance state
        for (int tt = 0; tt < SUBT; ++tt) {
            zt[tt][n] = (_Float16)cur;
            const float4* u4 = (const float4*)(us + tt * NU);
            float v0 = 0.f, v1 = 0.f, v2 = 0.f, v3 = 0.f;
            #pragma unroll
            for (int q = 0; q < 8; ++q) {
                float4 uu = u4[q];
                v0 = fmaf(br[4 * q], uu.x, v0);
                v1 = fmaf(br[4 * q + 1], uu.y, v1);
                v2 = fmaf(br[4 * q + 2], uu.z, v2);
                v3 = fmaf(br[4 * q + 3], uu.w, v3);
            }
            cur = fmaf(ln, cur, (v0 + v1) + (v2 + v3));
        }
        // append u tile (f16) to zt rows
        for (int i = n; i < SUBT * NU; i += 256) {
            int tt = i >> 5, j = i & 31;
            zt[tt][NX + j] = (_Float16)us[i];
        }
        __syncthreads();

        // projection: y[t][iy] = sum_k zt[t][k] * wh[iy][k]  (K=288, f16 dot2, 2x2 tile)
        int iy2 = n & 15, tt2 = n >> 4;
        float a00 = 0.f, a01 = 0.f, a10 = 0.f, a11 = 0.f;
        const half8_t* z0p = (const half8_t*)&zt[tt2 * 2][0];
        const half8_t* z1p = (const half8_t*)&zt[tt2 * 2 + 1][0];
        const half8_t* w0p = (const half8_t*)&wh[iy2 * 2][0];
        const half8_t* w1p = (const half8_t*)&wh[iy2 * 2 + 1][0];
        #pragma unroll 4
        for (int k8 = 0; k8 < KW / 8; ++k8) {
            union { half8_t v; half2_t h2[4]; } uz0, uz1, uw0, uw1;
            uz0.v = z0p[k8]; uz1.v = z1p[k8]; uw0.v = w0p[k8]; uw1.v = w1p[k8];
            #pragma unroll
            for (int p = 0; p < 4; ++p) {
                a00 = __builtin_amdgcn_fdot2(uz0.h2[p], uw0.h2[p], a00, false);
                a01 = __builtin_amdgcn_fdot2(uz0.h2[p], uw1.h2[p], a01, false);
                a10 = __builtin_amdgcn_fdot2(uz1.h2[p], uw0.h2[p], a10, false);
                a11 = __builtin_amdgcn_fdot2(uz1.h2[p], uw1.h2[p], a11, false);
            }
        }
        int trow = sub * SUBT + tt2 * 2;
        *(float2*)&yg[(size_t)trow * NY + iy2 * 2] = make_float2(a00, a01);
        *(float2*)&yg[(size_t)(trow + 1) * NY + iy2 * 2] = make_float2(a10, a11);
        __syncthreads();
    }
}

extern "C" void kernel_launch(void* const* d_in, const int* in_sizes, int n_in,
                              void* d_out, int out_size, void* d_ws, size_t ws_size,
                              hipStream_t stream) {
    (void)in_sizes; (void)n_in; (void)out_size; (void)ws_size;
    const float* x0  = (const float*)d_in[0];
    const float* u   = (const float*)d_in[1];
    const float* Q   = (const float*)d_in[2];
    const float* lam = (const float*)d_in[3];
    const float* Bm  = (const float*)d_in[4];
    const float* C   = (const float*)d_in[5];
    const float* D   = (const float*)d_in[6];
    float* y = (float*)d_out;

    char* ws = (char*)d_ws;
    float*    Bz = (float*)(ws);                 // 32768 B
    float*    z0 = (float*)(ws + 32768);         // 16384 B
    _Float16* Wh = (_Float16*)(ws + 49152);      // 18432 B
    float*    S  = (float*)(ws + 67584);         // 524288 B  (total ~592 KB)

    k_pre   <<<84, 256, 0, stream>>>(x0, Q, Bm, C, D, Bz, z0, Wh);
    k_phase1<<<BATCH * NC, 256, 0, stream>>>(u, lam, Bz, S);
    k_phase3<<<BATCH * NC, 256, 0, stream>>>(u, lam, Bz, z0, S, Wh, y);
}

// Round 2
// 120.577 us; speedup vs baseline: 2.1563x; 2.1563x over previous
//
#include <hip/hip_runtime.h>

typedef _Float16 half4_t __attribute__((ext_vector_type(4)));
typedef _Float16 half8_t __attribute__((ext_vector_type(8)));
typedef float f32x4 __attribute__((ext_vector_type(4)));

constexpr int NX = 256, NU = 32, NY = 32, BATCH = 16, T = 8192;
constexpr int NC = 64, L = 128;       // 64 chunks of 128 steps
constexpr int SUBT = 32, NSUB = L / SUBT;
constexpr int KW = NX + NU;           // 288 projection K: [z | u]
constexpr int ZROW = 264;             // zt row pitch (halves): 528B, 16B-aligned
constexpr int VROW = 260;             // vt row pitch (halves): 520B -> conflict-free C-writes

// ---------- pre: Bzh=(Q^T Bm) f16, Wh=[CQ|D] f16, z0=x0 Q f32 ; split-K x4 ----------
__global__ __launch_bounds__(256) void k_pre(
    const float* __restrict__ x0, const float* __restrict__ Q,
    const float* __restrict__ Bm, const float* __restrict__ C,
    const float* __restrict__ D,
    _Float16* __restrict__ Bzh, _Float16* __restrict__ Wh, float* __restrict__ z0)
{
    int o = blockIdx.x * 64 + (threadIdx.x >> 2);
    int p = threadIdx.x & 3;
    if (o >= 20480) {                                   // D copy
        if (p == 0) {
            int g = o - 20480, iy = g >> 5, j = g & 31;
            Wh[iy * KW + NX + j] = (_Float16)D[iy * NU + j];
        }
        return;
    }
    float s = 0.f;
    int k0 = p * 64;
    if (o < 8192) {                                     // Bzh[n][j] = sum_k Q[k][n] Bm[k][j]
        int n = o >> 5, j = o & 31;
        for (int k = k0; k < k0 + 64; ++k) s = fmaf(Q[k * NX + n], Bm[k * NU + j], s);
    } else if (o < 16384) {                             // CQ[iy][nn]
        int g = o - 8192; int iy = g >> 8, nn = g & 255;
        for (int k = k0; k < k0 + 64; ++k) s = fmaf(C[iy * NX + k], Q[k * NX + nn], s);
    } else {                                            // z0[b][nn]
        int g = o - 16384; int b = g >> 8, nn = g & 255;
        for (int k = k0; k < k0 + 64; ++k) s = fmaf(x0[b * NX + k], Q[k * NX + nn], s);
    }
    s += __shfl_xor(s, 1);
    s += __shfl_xor(s, 2);
    if (p == 0) {
        if (o < 8192) {
            Bzh[o] = (_Float16)s;                       // row n*32 + j layout
        } else if (o < 16384) {
            int g = o - 8192; int iy = g >> 8, nn = g & 255;
            Wh[iy * KW + nn] = (_Float16)s;
        } else {
            z0[o - 16384] = s;
        }
    }
}

// ---------- phase 1: v via MFMA -> LDS, local scan -> chunk end state S ----------
__global__ __launch_bounds__(256) void k_phase1(
    const float* __restrict__ u, const float* __restrict__ lam,
    const _Float16* __restrict__ Bzh, float* __restrict__ S)
{
    __shared__ __align__(16) _Float16 ut[SUBT][32];     // u tile f16 (A operand)
    __shared__ _Float16 vt[SUBT][VROW];                 // v tile f16

    const int b = blockIdx.x >> 6, c = blockIdx.x & 63, n = threadIdx.x;
    const int wave = n >> 6, lane = n & 63, m16 = lane & 15, quad = lane >> 4;
    const int tw = wave & 1, ng = wave >> 1;

    half8_t bfrag[8];                                   // Bz rows as B fragments
    #pragma unroll
    for (int i = 0; i < 8; ++i)
        bfrag[i] = *(const half8_t*)&Bzh[(ng * 128 + i * 16 + m16) * NU + quad * 8];

    float ln = lam[n];
    float cur = 0.f;
    const float* ug = u + ((size_t)(b * T) + (size_t)c * L) * NU;

    for (int sub = 0; sub < NSUB; ++sub) {
        {   // stage u tile (32t x 32j) as f16
            float4 uu = *(const float4*)(ug + (size_t)sub * SUBT * NU + n * 4);
            half4_t h; h.x = (_Float16)uu.x; h.y = (_Float16)uu.y;
            h.z = (_Float16)uu.z; h.w = (_Float16)uu.w;
            *(half4_t*)&ut[n >> 3][(n & 7) * 4] = h;
        }
        __syncthreads();
        half8_t af = *(const half8_t*)&ut[tw * 16 + m16][quad * 8];
        #pragma unroll
        for (int i = 0; i < 8; ++i) {
            f32x4 z4 = {0.f, 0.f, 0.f, 0.f};
            f32x4 va = __builtin_amdgcn_mfma_f32_16x16x32_f16(af, bfrag[i], z4, 0, 0, 0);
            int nn = ng * 128 + i * 16 + m16;
            #pragma unroll
            for (int r = 0; r < 4; ++r)
                vt[tw * 16 + quad * 4 + r][nn] = (_Float16)va[r];
        }
        __syncthreads();
        #pragma unroll
        for (int tt = 0; tt < SUBT; ++tt)
            cur = fmaf(ln, cur, (float)vt[tt][n]);
        __syncthreads();
    }
    S[(size_t)blockIdx.x * NX + n] = cur;
}

// ---------- phase 2: chunk-start prefix P_c = lam^L P_{c-1} + S_{c-1} ----------
__global__ __launch_bounds__(256) void k_phase2(
    const float* __restrict__ z0, const float* __restrict__ lam,
    const float* __restrict__ S, float* __restrict__ P)
{
    int b = blockIdx.x, n = threadIdx.x;
    float ln = lam[n], lamL = ln;
    #pragma unroll
    for (int i = 0; i < 7; ++i) lamL *= lamL;           // ln^128
    float cur = z0[b * NX + n];
    P[(size_t)(b * NC) * NX + n] = cur;
    for (int c = 1; c < NC; ++c) {
        cur = fmaf(lamL, cur, S[(size_t)(b * NC + c - 1) * NX + n]);
        P[(size_t)(b * NC + c) * NX + n] = cur;
    }
}

// ---------- phase 3: v-MFMA -> scan (record z_prev) -> projection MFMA -> y ----------
__global__ __launch_bounds__(256) void k_phase3(
    const float* __restrict__ u, const float* __restrict__ lam,
    const _Float16* __restrict__ Bzh, const _Float16* __restrict__ Wh,
    const float* __restrict__ P, float* __restrict__ y)
{
    __shared__ __align__(16) _Float16 ut[SUBT][32];
    __shared__ _Float16 vt[SUBT][VROW];
    __shared__ __align__(16) _Float16 zt[SUBT][ZROW];

    const int b = blockIdx.x >> 6, c = blockIdx.x & 63, n = threadIdx.x;
    const int wave = n >> 6, lane = n & 63, m16 = lane & 15, quad = lane >> 4;
    const int tw = wave & 1, ng = wave >> 1;            // v-MFMA split; proj: yw=ng, ttile=tw

    half8_t bfrag[8];
    #pragma unroll
    for (int i = 0; i < 8; ++i)
        bfrag[i] = *(const half8_t*)&Bzh[(ng * 128 + i * 16 + m16) * NU + quad * 8];
    half8_t wfrag[9];                                   // W=[Cz|D] rows as B fragments
    #pragma unroll
    for (int kk = 0; kk < 9; ++kk)
        wfrag[kk] = *(const half8_t*)&Wh[(ng * 16 + m16) * KW + kk * 32 + quad * 8];

    float ln = lam[n];
    float cur = P[(size_t)(b * NC + c) * NX + n];       // state at chunk start
    const float* ug = u + ((size_t)(b * T) + (size_t)c * L) * NU;
    float* yg = y + ((size_t)(b * T) + (size_t)c * L) * NY;

    for (int sub = 0; sub < NSUB; ++sub) {
        {   // stage u tile
            float4 uu = *(const float4*)(ug + (size_t)sub * SUBT * NU + n * 4);
            half4_t h; h.x = (_Float16)uu.x; h.y = (_Float16)uu.y;
            h.z = (_Float16)uu.z; h.w = (_Float16)uu.w;
            *(half4_t*)&ut[n >> 3][(n & 7) * 4] = h;
        }
        __syncthreads();
        // v = u @ Bz^T via MFMA
        half8_t af = *(const half8_t*)&ut[tw * 16 + m16][quad * 8];
        #pragma unroll
        for (int i = 0; i < 8; ++i) {
            f32x4 z4 = {0.f, 0.f, 0.f, 0.f};
            f32x4 va = __builtin_amdgcn_mfma_f32_16x16x32_f16(af, bfrag[i], z4, 0, 0, 0);
            int nn = ng * 128 + i * 16 + m16;
            #pragma unroll
            for (int r = 0; r < 4; ++r)
                vt[tw * 16 + quad * 4 + r][nn] = (_Float16)va[r];
        }
        __syncthreads();
        // serial scan; record z_prev rows in A-operand layout
        #pragma unroll
        for (int tt = 0; tt < SUBT; ++tt) {
            zt[tt][n] = (_Float16)cur;
            cur = fmaf(ln, cur, (float)vt[tt][n]);
        }
        __syncthreads();
        // y = [z|u] @ [Cz|D]^T via MFMA (K=288)
        f32x4 acc = {0.f, 0.f, 0.f, 0.f};
        #pragma unroll
        for (int kk = 0; kk < 8; ++kk) {
            half8_t az = *(const half8_t*)&zt[tw * 16 + m16][kk * 32 + quad * 8];
            acc = __builtin_amdgcn_mfma_f32_16x16x32_f16(az, wfrag[kk], acc, 0, 0, 0);
        }
        {
            half8_t au = *(const half8_t*)&ut[tw * 16 + m16][quad * 8];
            acc = __builtin_amdgcn_mfma_f32_16x16x32_f16(au, wfrag[8], acc, 0, 0, 0);
        }
        #pragma unroll
        for (int r = 0; r < 4; ++r)
            yg[(size_t)(sub * SUBT + tw * 16 + quad * 4 + r) * NY + ng * 16 + m16] = acc[r];
        __syncthreads();
    }
}

extern "C" void kernel_launch(void* const* d_in, const int* in_sizes, int n_in,
                              void* d_out, int out_size, void* d_ws, size_t ws_size,
                              hipStream_t stream) {
    (void)in_sizes; (void)n_in; (void)out_size; (void)ws_size;
    const float* x0  = (const float*)d_in[0];
    const float* u   = (const float*)d_in[1];
    const float* Q   = (const float*)d_in[2];
    const float* lam = (const float*)d_in[3];
    const float* Bm  = (const float*)d_in[4];
    const float* C   = (const float*)d_in[5];
    const float* D   = (const float*)d_in[6];
    float* y = (float*)d_out;

    char* ws = (char*)d_ws;
    _Float16* Bzh = (_Float16*)(ws);                    // 16384 B
    _Float16* Wh  = (_Float16*)(ws + 16384);            // 18432 B
    float*    z0  = (float*)(ws + 34816);               // 16384 B
    float*    S   = (float*)(ws + 51200);               // 1 MB
    float*    P   = (float*)(ws + 51200 + 1048576);     // 1 MB (total ~2.1 MB)

    k_pre   <<<336, 256, 0, stream>>>(x0, Q, Bm, C, D, Bzh, Wh, z0);
    k_phase1<<<BATCH * NC, 256, 0, stream>>>(u, lam, Bzh, S);
    k_phase2<<<BATCH, 256, 0, stream>>>(z0, lam, S, P);
    k_phase3<<<BATCH * NC, 256, 0, stream>>>(u, lam, Bzh, Wh, P, y);
}

// Round 3
// 119.848 us; speedup vs baseline: 2.1695x; 1.0061x over previous
//
#include <hip/hip_runtime.h>

typedef _Float16 half4_t __attribute__((ext_vector_type(4)));
typedef _Float16 half8_t __attribute__((ext_vector_type(8)));
typedef float f32x4 __attribute__((ext_vector_type(4)));

constexpr int NX = 256, NU = 32, NY = 32, BATCH = 16, T = 8192;
constexpr int NC = 64, L = 128;       // 64 chunks of 128 steps
constexpr int SUBT = 32, NSUB = L / SUBT;
constexpr int KW = NX + NU;           // 288 projection K: [z | u]
constexpr int VP = 40;                // V'^T pitch in halves (80B rows, 16B-aligned)
constexpr int ZP = 264;               // zt pitch in halves (528B rows, 16B-aligned)
constexpr int POOLSZ = NX * VP;       // 10240 halves >= 32*ZP = 8448

// ---------- pre: Bzh=(Q^T Bm) f16, Wh=[CQ|D] f16, z0=x0 Q f32 ; split-K x4 ----------
__global__ __launch_bounds__(256) void k_pre(
    const float* __restrict__ x0, const float* __restrict__ Q,
    const float* __restrict__ Bm, const float* __restrict__ C,
    const float* __restrict__ D,
    _Float16* __restrict__ Bzh, _Float16* __restrict__ Wh, float* __restrict__ z0)
{
    int o = blockIdx.x * 64 + (threadIdx.x >> 2);
    int p = threadIdx.x & 3;
    if (o >= 20480) {                                   // D copy
        if (p == 0) {
            int g = o - 20480, iy = g >> 5, j = g & 31;
            Wh[iy * KW + NX + j] = (_Float16)D[iy * NU + j];
        }
        return;
    }
    float s = 0.f;
    int k0 = p * 64;
    if (o < 8192) {                                     // Bzh[n][j] = sum_k Q[k][n] Bm[k][j]
        int n = o >> 5, j = o & 31;
        for (int k = k0; k < k0 + 64; ++k) s = fmaf(Q[k * NX + n], Bm[k * NU + j], s);
    } else if (o < 16384) {                             // CQ[iy][nn]
        int g = o - 8192; int iy = g >> 8, nn = g & 255;
        for (int k = k0; k < k0 + 64; ++k) s = fmaf(C[iy * NX + k], Q[k * NX + nn], s);
    } else {                                            // z0[b][nn]
        int g = o - 16384; int b = g >> 8, nn = g & 255;
        for (int k = k0; k < k0 + 64; ++k) s = fmaf(x0[b * NX + k], Q[k * NX + nn], s);
    }
    s += __shfl_xor(s, 1);
    s += __shfl_xor(s, 2);
    if (p == 0) {
        if (o < 8192) {
            Bzh[o] = (_Float16)s;
        } else if (o < 16384) {
            int g = o - 8192; int iy = g >> 8, nn = g & 255;
            Wh[iy * KW + nn] = (_Float16)s;
        } else {
            z0[o - 16384] = s;
        }
    }
}

// ---------- phase 1: v via MFMA, weighted-sum reduction -> chunk end state S ----------
// S_n = sum_{s<L} lam_n^{L-1-s} v_s[n], accumulated entirely in C-layout registers.
__global__ __launch_bounds__(256) void k_phase1(
    const float* __restrict__ u, const float* __restrict__ lam,
    const _Float16* __restrict__ Bzh, float* __restrict__ S)
{
    __shared__ __align__(16) _Float16 ut[2][SUBT][32];  // swizzled, double-buffered

    const int b = blockIdx.x >> 6, c = blockIdx.x & 63, tid = threadIdx.x;
    const int w = tid >> 6, lane = tid & 63, m16 = lane & 15, quad = lane >> 4;

    half8_t bfrag[4];
    #pragma unroll
    for (int i = 0; i < 4; ++i)
        bfrag[i] = *(const half8_t*)&Bzh[((4 * w + i) * 16 + m16) * NU + quad * 8];

    float wr[4][4], wt16[4], l32[4], acc[4];
    #pragma unroll
    for (int i = 0; i < 4; ++i) {
        float la = lam[(4 * w + i) * 16 + m16];
        float p2 = la * la, p4 = p2 * p2, p8 = p4 * p4, p16 = p8 * p8;
        float inv1 = 1.0f / la;
        float inv4 = (inv1 * inv1) * (inv1 * inv1);
        float pq = 1.0f;
        if (quad & 1) pq *= inv4;
        if (quad & 2) pq *= inv4 * inv4;
        float w0 = (p16 * p8 * p4 * p2 * la) * pq;      // lam^(31-4q)
        wr[i][0] = w0;
        wr[i][1] = w0 * inv1;
        wr[i][2] = wr[i][1] * inv1;
        wr[i][3] = wr[i][2] * inv1;
        wt16[i] = 1.0f / p16;                            // lam^-16
        l32[i] = p16 * p16;                              // lam^32
        acc[i] = 0.f;
    }

    const float* ug = u + ((size_t)(b * T) + (size_t)c * L) * NU;

    for (int sub = 0; sub < NSUB; ++sub) {
        {   // stage u tile (32t x 32j) f16, swizzled: col' = (col + (t&3)*8) & 31
            float4 uu = *(const float4*)(ug + (size_t)sub * SUBT * NU + tid * 4);
            int tr = tid >> 3, cb = ((tid & 7) * 4 + (tr & 3) * 8) & 31;
            half4_t h; h.x = (_Float16)uu.x; h.y = (_Float16)uu.y;
            h.z = (_Float16)uu.z; h.w = (_Float16)uu.w;
            *(half4_t*)&ut[sub & 1][tr][cb] = h;
        }
        __syncthreads();
        int rot = (m16 & 3) * 8;
        half8_t af0 = *(const half8_t*)&ut[sub & 1][m16][(quad * 8 + rot) & 31];
        half8_t af1 = *(const half8_t*)&ut[sub & 1][16 + m16][(quad * 8 + rot) & 31];
        #pragma unroll
        for (int i = 0; i < 4; ++i) {
            f32x4 z4 = {0.f, 0.f, 0.f, 0.f};
            f32x4 v0 = __builtin_amdgcn_mfma_f32_16x16x32_f16(af0, bfrag[i], z4, 0, 0, 0);
            f32x4 v1 = __builtin_amdgcn_mfma_f32_16x16x32_f16(af1, bfrag[i], z4, 0, 0, 0);
            float s0 = wr[i][0] * v0[0] + wr[i][1] * v0[1] + wr[i][2] * v0[2] + wr[i][3] * v0[3];
            float s1 = wr[i][0] * v1[0] + wr[i][1] * v1[1] + wr[i][2] * v1[2] + wr[i][3] * v1[3];
            acc[i] = fmaf(l32[i], acc[i], fmaf(wt16[i], s1, s0));
        }
    }
    #pragma unroll
    for (int i = 0; i < 4; ++i) {
        acc[i] += __shfl_xor(acc[i], 16);
        acc[i] += __shfl_xor(acc[i], 32);
    }
    float out = quad == 0 ? acc[0] : quad == 1 ? acc[1] : quad == 2 ? acc[2] : acc[3];
    S[(size_t)blockIdx.x * NX + (4 * w + quad) * 16 + m16] = out;
}

// ---------- phase 2: chunk-start prefix P_c = lam^L P_{c-1} + S_{c-1} ----------
__global__ __launch_bounds__(256) void k_phase2(
    const float* __restrict__ z0, const float* __restrict__ lam,
    const float* __restrict__ S, float* __restrict__ P)
{
    int b = blockIdx.x, n = threadIdx.x;
    float ln = lam[n], lamL = ln;
    #pragma unroll
    for (int i = 0; i < 7; ++i) lamL *= lamL;           // ln^128
    float cur = z0[b * NX + n];
    P[(size_t)(b * NC) * NX + n] = cur;
    for (int c = 1; c < NC; ++c) {
        cur = fmaf(lamL, cur, S[(size_t)(b * NC + c - 1) * NX + n]);
        P[(size_t)(b * NC + c) * NX + n] = cur;
    }
}

// ---------- phase 3: v-MFMA -> Tri-MFMA scan -> projection MFMA -> y ----------
__global__ __launch_bounds__(256) void k_phase3(
    const float* __restrict__ u, const float* __restrict__ lam,
    const _Float16* __restrict__ Bzh, const _Float16* __restrict__ Wh,
    const float* __restrict__ P, float* __restrict__ y)
{
    __shared__ __align__(16) _Float16 ut[2][SUBT][32];  // 4 KB
    __shared__ __align__(16) _Float16 pool[POOLSZ];     // 20.5 KB: V'^T then zt

    const int b = blockIdx.x >> 6, c = blockIdx.x & 63, tid = threadIdx.x;
    const int w = tid >> 6, lane = tid & 63, m16 = lane & 15, quad = lane >> 4;
    const int tw = w & 1, yw = w >> 1;                  // proj: t-tile, y-tile

    half8_t bfrag[4];
    #pragma unroll
    for (int i = 0; i < 4; ++i)
        bfrag[i] = *(const half8_t*)&Bzh[((4 * w + i) * 16 + m16) * NU + quad * 8];
    half8_t wfrag[9];
    #pragma unroll
    for (int kk = 0; kk < 9; ++kk)
        wfrag[kk] = *(const half8_t*)&Wh[(yw * 16 + m16) * KW + kk * 32 + quad * 8];
    half8_t triA[2];                                    // Tri[t][s] = (s < t), t = tt*16+m16
    #pragma unroll
    for (int tt = 0; tt < 2; ++tt) {
        #pragma unroll
        for (int j = 0; j < 8; ++j)
            triA[tt][j] = (_Float16)((quad * 8 + j < tt * 16 + m16) ? 1.f : 0.f);
    }

    // per-col lambda powers
    float lamn[4], inv1[4], iq[4], i16p[4], fq[4], f16p[4], l32[4], p[4];
    #pragma unroll
    for (int i = 0; i < 4; ++i) {
        int ni = (4 * w + i) * 16 + m16;
        float la = lam[ni];
        lamn[i] = la;
        float p2 = la * la, p4 = p2 * p2, p8 = p4 * p4, p16 = p8 * p8;
        float iv = 1.0f / la;
        inv1[i] = iv;
        float iv4 = (iv * iv) * (iv * iv);
        float pqi = 1.0f, pqf = 1.0f;
        if (quad & 1) { pqi *= iv4; pqf *= p4; }
        if (quad & 2) { pqi *= iv4 * iv4; pqf *= p8; }
        iq[i] = iv * pqi;                               // lam^-(1+4q)
        fq[i] = pqf;                                    // lam^(4q)
        i16p[i] = 1.0f / p16;                           // lam^-16
        f16p[i] = p16;                                  // lam^16
        l32[i] = p16 * p16;                             // lam^32
        p[i] = P[(size_t)(b * NC + c) * NX + ni];
    }

    const float* ug = u + ((size_t)(b * T) + (size_t)c * L) * NU;
    float* yg = y + ((size_t)(b * T) + (size_t)c * L) * NY;

    for (int sub = 0; sub < NSUB; ++sub) {
        {   // stage u tile (swizzled, dbuf)
            float4 uu = *(const float4*)(ug + (size_t)sub * SUBT * NU + tid * 4);
            int tr = tid >> 3, cb = ((tid & 7) * 4 + (tr & 3) * 8) & 31;
            half4_t h; h.x = (_Float16)uu.x; h.y = (_Float16)uu.y;
            h.z = (_Float16)uu.z; h.w = (_Float16)uu.w;
            *(half4_t*)&ut[sub & 1][tr][cb] = h;
        }
        __syncthreads();                                 // B1

        // v = u @ Bz^T ; scale V'[s] = lam^-(1+s) v_s ; store V'^T ; partial sums
        int rot = (m16 & 3) * 8;
        half8_t af0 = *(const half8_t*)&ut[sub & 1][m16][(quad * 8 + rot) & 31];
        half8_t af1 = *(const half8_t*)&ut[sub & 1][16 + m16][(quad * 8 + rot) & 31];
        float partial[4];
        #pragma unroll
        for (int i = 0; i < 4; ++i) {
            int ni = (4 * w + i) * 16 + m16;
            f32x4 z4 = {0.f, 0.f, 0.f, 0.f};
            f32x4 v0 = __builtin_amdgcn_mfma_f32_16x16x32_f16(af0, bfrag[i], z4, 0, 0, 0);
            f32x4 v1 = __builtin_amdgcn_mfma_f32_16x16x32_f16(af1, bfrag[i], z4, 0, 0, 0);
            float ps = 0.f;
            float sc = iq[i];                            // lam^-(1+4q+r), r running
            half4_t h0, h1;
            #pragma unroll
            for (int r = 0; r < 4; ++r) {
                float a0 = v0[r] * sc;
                float a1 = v1[r] * (sc * i16p[i]);
                ps += a0 + a1;
                h0[r] = (_Float16)a0;
                h1[r] = (_Float16)a1;
                sc *= inv1[i];
            }
            partial[i] = ps;
            *(half4_t*)&pool[ni * VP + quad * 4] = h0;
            *(half4_t*)&pool[ni * VP + 16 + quad * 4] = h1;
        }
        __syncthreads();                                 // B2

        // Z' = Tri @ V'
        f32x4 zp0[4], zp1[4];
        #pragma unroll
        for (int i = 0; i < 4; ++i) {
            int ni = (4 * w + i) * 16 + m16;
            half8_t bV = *(const half8_t*)&pool[ni * VP + quad * 8];
            f32x4 z4 = {0.f, 0.f, 0.f, 0.f};
            zp0[i] = __builtin_amdgcn_mfma_f32_16x16x32_f16(triA[0], bV, z4, 0, 0, 0);
            zp1[i] = __builtin_amdgcn_mfma_f32_16x16x32_f16(triA[1], bV, z4, 0, 0, 0);
        }
        __syncthreads();                                 // B3 (pool: V'^T -> zt)

        // z_prev[t] = lam^t (p + Z'[t]) ; store zt rows (A layout) as f16
        #pragma unroll
        for (int i = 0; i < 4; ++i) {
            int ni = (4 * w + i) * 16 + m16;
            float f = fq[i];                             // lam^(4q+r), r running
            #pragma unroll
            for (int r = 0; r < 4; ++r) {
                float zv0 = f * (p[i] + zp0[i][r]);
                float zv1 = (f * f16p[i]) * (p[i] + zp1[i][r]);
                pool[(quad * 4 + r) * ZP + ni] = (_Float16)zv0;
                pool[(16 + quad * 4 + r) * ZP + ni] = (_Float16)zv1;
                f *= lamn[i];
            }
        }
        // carry update: p <- lam^32 (p + sum_s lam^-(1+s) v_s)
        #pragma unroll
        for (int i = 0; i < 4; ++i) {
            float ps = partial[i];
            ps += __shfl_xor(ps, 16);
            ps += __shfl_xor(ps, 32);
            p[i] = l32[i] * (p[i] + ps);
        }
        __syncthreads();                                 // B4

        // y = [z_prev | u] @ [Cz | D]^T
        f32x4 acc = {0.f, 0.f, 0.f, 0.f};
        #pragma unroll
        for (int kk = 0; kk < 8; ++kk) {
            half8_t az = *(const half8_t*)&pool[(tw * 16 + m16) * ZP + kk * 32 + quad * 8];
            acc = __builtin_amdgcn_mfma_f32_16x16x32_f16(az, wfrag[kk], acc, 0, 0, 0);
        }
        {
            half8_t au = *(const half8_t*)&ut[sub & 1][tw * 16 + m16][(quad * 8 + rot) & 31];
            acc = __builtin_amdgcn_mfma_f32_16x16x32_f16(au, wfrag[8], acc, 0, 0, 0);
        }
        #pragma unroll
        for (int r = 0; r < 4; ++r)
            yg[(size_t)(sub * SUBT + tw * 16 + quad * 4 + r) * NY + yw * 16 + m16] = acc[r];
    }
}

extern "C" void kernel_launch(void* const* d_in, const int* in_sizes, int n_in,
                              void* d_out, int out_size, void* d_ws, size_t ws_size,
                              hipStream_t stream) {
    (void)in_sizes; (void)n_in; (void)out_size; (void)ws_size;
    const float* x0  = (const float*)d_in[0];
    const float* u   = (const float*)d_in[1];
    const float* Q   = (const float*)d_in[2];
    const float* lam = (const float*)d_in[3];
    const float* Bm  = (const float*)d_in[4];
    const float* C   = (const float*)d_in[5];
    const float* D   = (const float*)d_in[6];
    float* y = (float*)d_out;

    char* ws = (char*)d_ws;
    _Float16* Bzh = (_Float16*)(ws);                    // 16384 B
    _Float16* Wh  = (_Float16*)(ws + 16384);            // 18432 B
    float*    z0  = (float*)(ws + 34816);               // 16384 B
    float*    S   = (float*)(ws + 51200);               // 1 MB
    float*    P   = (float*)(ws + 51200 + 1048576);     // 1 MB

    k_pre   <<<336, 256, 0, stream>>>(x0, Q, Bm, C, D, Bzh, Wh, z0);
    k_phase1<<<BATCH * NC, 256, 0, stream>>>(u, lam, Bzh, S);
    k_phase2<<<BATCH, 256, 0, stream>>>(z0, lam, S, P);
    k_phase3<<<BATCH * NC, 256, 0, stream>>>(u, lam, Bzh, Wh, P, y);
}